// Round 13
// baseline (693.687 us; speedup 1.0000x reference)
//
#include <hip/hip_runtime.h>
#include <cstdint>
#include <cfloat>
#include <cstddef>

// ---------------- problem constants ----------------
constexpr int BATCH  = 2;
constexpr int V      = 12000;
constexpr int VP     = V + 1;        // 12001
constexpr int M_ROWS = BATCH * VP;   // 24002
constexpr int L_SP   = 16;

typedef _Float16 half_t;
typedef _Float16 half8 __attribute__((ext_vector_type(8)));
typedef float floatx4 __attribute__((ext_vector_type(4)));

// async global->LDS, 16B per lane (global_load_lds_dwordx4)
__device__ __forceinline__ void async_cp16(const void* g, void* l) {
    __builtin_amdgcn_global_load_lds(
        (const __attribute__((address_space(1))) unsigned int*)g,
        (__attribute__((address_space(3))) unsigned int*)l, 16, 0, 0);
}

// ---------------------------------------------------------------------------
// f16 MFMA GEMM — R11 structure (single LDS buffer, per-iter barrier pair,
// idx VGPR prefetch, XOR swizzle; conflicts==0) generalized to BM x BN tiles.
// R12 lesson: gather layers are L2-miss-FABRIC-bound; FETCH ~ passes x 8XCD x
// f x table. So: res1 keeps BM=64/BN=64 (best measured, 4 passes but best f);
// ress convs go BM=16/BN=128 -> ONE gather pass at unchanged 5.9 blocks/CU
// (grid 1501, LDS 18KB).
// Wave layout: BM>=32 -> 2x2 quadrants; BM=16 -> 1x4 (wm=0, wn=w*32).
//   GATHER: A row m=(b,v) = concat_l act[b*VP + idx[v][l], 0:C], C=2^LGC
//   else  : A is [M][KA] fp16 row-major (KA % 64 == 0); LGC=0
// Wt is [N][K] fp16 (pre-transposed). Epilogue: fp32 acc + bias(f32) +
// res(f16), optional relu, rows v==VP-1 zeroed when mask. Output fp16.
// Requires: N % BN == 0, K % 64 == 0, (GATHER) 64 | C and K/C == 16.
// ---------------------------------------------------------------------------
template<bool GATHER, int BM, int BN, int LGC>
__global__ __launch_bounds__(256, 4)
void gemm_mfma(const half_t* __restrict__ A, const half_t* __restrict__ Wt,
               const float* __restrict__ bias, const half_t* __restrict__ res,
               const int* __restrict__ idx, half_t* __restrict__ out,
               int M, int N, int K, int KA, int relu, int mask)
{
    constexpr int AI = (BM >= 32) ? (BM / 32) : 1;   // A stage instrs (BM=16: half threads)
    constexpr int NB = BN / 32;                      // B stage instrs per thread
    constexpr int WROWS = (BM >= 32) ? 2 : 1;        // waves along M
    constexpr int AFR = (BM / WROWS) / 16;           // A frags per wave
    constexpr int BFR = (BN / (4 / WROWS)) / 16;     // B frags per wave
    __shared__ half_t As[BM * 64];
    __shared__ half_t Bs[BN * 64];

    const int tid  = threadIdx.x;
    const int lane = tid & 63;
    const int w    = tid >> 6;
    const int bm   = blockIdx.x, bn = blockIdx.y;

    // swizzled 16B-chunk offset (halfs): lane stages chunk (lane&7)^((lane>>3)&7)
    const int goff = (((lane & 7) ^ ((lane >> 3) & 7)) << 3);
    const int rsub = lane >> 3;          // row within 8-row stage group

    // ---- B staging: BN rows x 128B; wave w -> instr-blocks w+4*bi ----
    const half_t* wp[NB];
    half_t* lB[NB];
#pragma unroll
    for (int bi = 0; bi < NB; ++bi) {
        const int blk = w + (bi << 2);
        wp[bi] = Wt + (size_t)(bn * BN + (blk << 3) + rsub) * K + goff;
        lB[bi] = &Bs[(size_t)((blk << 6) + lane) * 8];
    }

    // ---- A staging: BM rows; wave w -> instr-blocks w+4*ai ----
    const bool astage = (BM >= 32) || (tid < 128);
    int vv[AI], abase[AI];
    const half_t* aP[AI];
    half_t* lA[AI];
#pragma unroll
    for (int ai = 0; ai < AI; ++ai) {
        const int blk = w + (ai << 2);
        int m = bm * BM + (blk << 3) + rsub;
        if (m >= M) m = M - 1;
        const int b = m / VP;
        vv[ai] = m - b * VP;
        abase[ai] = b * VP;
        aP[ai] = GATHER ? nullptr : (A + (size_t)m * KA + goff);
        lA[ai] = &As[(size_t)(((blk << 6) + lane) & (BM * 8 - 1)) * 8];
    }

    // ---- compute mapping ----
    const int wm = (WROWS == 2) ? (w >> 1) * (BM / 2) : 0;
    const int wn = (WROWS == 2) ? (w & 1) * (BN / 2) : w * (BN / 4);
    const int fr = lane & 15;            // A row / B col within 16-tile
    const int q  = lane >> 4;            // k-quad
    const int f7 = fr & 7;

    floatx4 acc[AFR][BFR] = {};

    auto compute = [&]() {
#pragma unroll
        for (int s = 0; s < 2; ++s) {
            const int ck = ((((s << 2) | q) ^ f7) << 3);   // swizzled chunk (halfs)
            half8 af[AFR], bf[BFR];
#pragma unroll
            for (int i = 0; i < AFR; ++i)
                af[i] = *(const half8*)&As[(wm + (i << 4) + fr) * 64 + ck];
#pragma unroll
            for (int j = 0; j < BFR; ++j)
                bf[j] = *(const half8*)&Bs[(wn + (j << 4) + fr) * 64 + ck];
#pragma unroll
            for (int i = 0; i < AFR; ++i)
#pragma unroll
                for (int j = 0; j < BFR; ++j)
                    acc[i][j] = __builtin_amdgcn_mfma_f32_16x16x32_f16(af[i], bf[j], acc[i][j], 0, 0, 0);
        }
    };

    if (GATHER) {
        constexpr int NI = (1 << LGC) >> 6;   // BK=64 tiles per neighbor (4 or 2)
        constexpr int L  = 16;                // K / C
        int jc[AI], jn[AI];
#pragma unroll
        for (int ai = 0; ai < AI; ++ai) jc[ai] = idx[vv[ai] << 4];
#pragma unroll
        for (int ai = 0; ai < AI; ++ai) jn[ai] = idx[(vv[ai] << 4) + 1];
#pragma unroll 1
        for (int l = 0; l < L; ++l) {
            const half_t* g[AI];
#pragma unroll
            for (int ai = 0; ai < AI; ++ai)
                g[ai] = A + (((size_t)(abase[ai] + jc[ai])) << LGC) + goff;
            const int kb = l << LGC;
#pragma unroll
            for (int kc = 0; kc < NI; ++kc) {
                if (astage) {
#pragma unroll
                    for (int ai = 0; ai < AI; ++ai)
                        async_cp16(g[ai] + (kc << 6), lA[ai]);
                }
#pragma unroll
                for (int bi = 0; bi < NB; ++bi)
                    async_cp16(wp[bi] + kb + (kc << 6), lB[bi]);
                __syncthreads();   // drains staging (and the jn prefetch)
                compute();
                __syncthreads();   // LDS reuse guard
            }
            // rotate idx: jn was prefetched a full group ago -> zero wait here
#pragma unroll
            for (int ai = 0; ai < AI; ++ai) jc[ai] = jn[ai];
            if (l + 2 < L) {
#pragma unroll
                for (int ai = 0; ai < AI; ++ai) jn[ai] = idx[(vv[ai] << 4) + l + 2];
            }
        }
    } else {
        const int nk = K >> 6;
        for (int t = 0; t < nk; ++t) {
            const int k0 = t << 6;
            if (astage) {
#pragma unroll
                for (int ai = 0; ai < AI; ++ai)
                    async_cp16(aP[ai] + k0, lA[ai]);
            }
#pragma unroll
            for (int bi = 0; bi < NB; ++bi)
                async_cp16(wp[bi] + k0, lB[bi]);
            __syncthreads();
            compute();
            __syncthreads();
        }
    }

    // epilogue: C/D layout col=lane&15, row=(lane>>4)*4+reg
    const int er = q << 2;
#pragma unroll
    for (int i = 0; i < AFR; ++i) {
#pragma unroll
        for (int j = 0; j < BFR; ++j) {
            const int n = bn * BN + wn + (j << 4) + fr;
            const floatx4 a = acc[i][j];
#pragma unroll
            for (int r = 0; r < 4; ++r) {
                const int m = bm * BM + wm + (i << 4) + er + r;
                if (m >= M) continue;
                float val = a[r];
                if (bias) val += bias[n];
                if (res)  val += (float)res[(size_t)m * N + n];
                if (relu) val = fmaxf(val, 0.f);
                const int vvm = m - (m / VP) * VP;
                if (mask && vvm == VP - 1) val = 0.f;
                out[(size_t)m * N + n] = (half_t)val;
            }
        }
    }
}

// ---------------------------------------------------------------------------
// weight convert + transpose fp32 [z][K][N] -> fp16 [z][N][Kpad] (zero-pad K)
// grid (ceil(Kpad/32), ceil(N/32), z), block 256 (32x8)
// ---------------------------------------------------------------------------
__global__ void wcvt(const float* __restrict__ in, half_t* __restrict__ out,
                     int K, int N, int Kpad)
{
    __shared__ float t[32][33];
    const size_t ioff = (size_t)blockIdx.z * K * N;
    const size_t ooff = (size_t)blockIdx.z * N * Kpad;
    const int k0 = blockIdx.x * 32, n0 = blockIdx.y * 32;
    const int tx = threadIdx.x & 31, ty = threadIdx.x >> 5;
#pragma unroll
    for (int r = 0; r < 4; ++r) {
        const int k = k0 + ty + r * 8;
        t[ty + r * 8][tx] = (k < K && n0 + tx < N) ? in[ioff + (size_t)k * N + n0 + tx] : 0.f;
    }
    __syncthreads();
#pragma unroll
    for (int r = 0; r < 4; ++r) {
        const int n = n0 + ty + r * 8;
        const int k = k0 + tx;
        if (n < N && k < Kpad) out[ooff + (size_t)n * Kpad + k] = (half_t)t[tx][ty + r * 8];
    }
}

// x [B][V][479] fp32 -> xh [B*VP][512] fp16, pad cols 479..511 and dummy rows = 0
__global__ void cvt_x(const float* __restrict__ x, half_t* __restrict__ xh)
{
    const int m = blockIdx.x;
    const int b = m / VP, v = m - b * VP;
    for (int k = threadIdx.x; k < 512; k += 256) {
        float val = (v < V && k < 479) ? x[((size_t)b * V + v) * 479 + k] : 0.f;
        xh[(size_t)m * 512 + k] = (half_t)val;
    }
}

// masked global max-pool, 2 stages. fs fp16 [B*VP][128]
__global__ void maxpool1(const half_t* __restrict__ fs, float* __restrict__ pmax)
{
    const int b = blockIdx.x, chunk = blockIdx.y;   // grid (2,32), block 128
    const int c = threadIdx.x;
    const int v0 = chunk * (V / 32);
    float m = -FLT_MAX;
    const half_t* p = fs + ((size_t)b * VP + v0) * 128 + c;
    for (int v = 0; v < V / 32; ++v) { m = fmaxf(m, (float)*p); p += 128; }
    pmax[((size_t)b * 32 + chunk) * 128 + c] = m;
}
__global__ void maxpool2(const float* __restrict__ pmax, half_t* __restrict__ gfs)
{
    const int b = blockIdx.x, c = threadIdx.x;      // grid 2, block 128
    float m = -FLT_MAX;
    for (int i = 0; i < 32; ++i) m = fmaxf(m, pmax[((size_t)b * 32 + i) * 128 + c]);
    gfs[b * 128 + c] = (half_t)m;
}

// h512[m] = [pfs(256) | fs(128) | gfs(128)*zp]  (fp16)
__global__ void concat_k(const half_t* __restrict__ pfs, const half_t* __restrict__ fs,
                         const half_t* __restrict__ gfs, half_t* __restrict__ h)
{
    const size_t i = (size_t)blockIdx.x * 256 + threadIdx.x;
    if (i >= (size_t)M_ROWS * 512) return;
    const int    n   = (int)(i & 511);
    const size_t row = i >> 9;
    const int    b   = (int)(row / VP);
    const int    v   = (int)(row - (size_t)b * VP);
    half_t val;
    if (n < 256)      val = pfs[row * 256 + n];
    else if (n < 384) val = fs[row * 128 + (n - 256)];
    else              val = (v == VP - 1) ? (half_t)0.f : gfs[b * 128 + (n - 384)];
    h[i] = val;
}

// final 128->3 (fp32 weights for accuracy), drop dummy vertex
__global__ void final_k(const half_t* __restrict__ h, const float* __restrict__ Wo3,
                        const float* __restrict__ bo3, float* __restrict__ out)
{
    __shared__ float wsm[384];
    __shared__ float b3[3];
    for (int t = threadIdx.x; t < 384; t += 256) wsm[t] = Wo3[t];
    if (threadIdx.x < 3) b3[threadIdx.x] = bo3[threadIdx.x];
    __syncthreads();

    const int gid = blockIdx.x * 256 + threadIdx.x;
    if (gid >= BATCH * V) return;
    const int b = gid / V;
    const int v = gid - b * V;
    const half_t* hr = h + ((size_t)b * VP + v) * 128;

    float o0 = b3[0], o1 = b3[1], o2 = b3[2];
#pragma unroll 4
    for (int c = 0; c < 128; ++c) {
        const float hv = (float)hr[c];
        o0 += hv * wsm[c * 3 + 0];
        o1 += hv * wsm[c * 3 + 1];
        o2 += hv * wsm[c * 3 + 2];
    }
    out[(size_t)gid * 3 + 0] = o0;
    out[(size_t)gid * 3 + 1] = o1;
    out[(size_t)gid * 3 + 2] = o2;
}

// ---------------------------------------------------------------------------
extern "C" void kernel_launch(void* const* d_in, const int* in_sizes, int n_in,
                              void* d_out, int out_size, void* d_ws, size_t ws_size,
                              hipStream_t stream)
{
    const float* x       = (const float*)d_in[0];
    const int*   sidx    = (const int*)  d_in[1];
    const float* W_point = (const float*)d_in[2];
    const float* res1_W  = (const float*)d_in[3];
    const float* res1_b  = (const float*)d_in[4];
    const float* W_mid   = (const float*)d_in[5];
    const float* ress_W  = (const float*)d_in[6];
    const float* ress_b  = (const float*)d_in[7];
    const float* Wo1     = (const float*)d_in[8];
    const float* bo1     = (const float*)d_in[9];
    const float* Wo2     = (const float*)d_in[10];
    const float* bo2     = (const float*)d_in[11];
    const float* Wo3     = (const float*)d_in[12];
    const float* bo3     = (const float*)d_in[13];
    float* out = (float*)d_out;

    // ---- workspace carve (bytes, 256B aligned) ----
    char* p = (char*)d_ws;
    auto alloc = [&](size_t bytes) { char* q = p; p += (bytes + 255) & ~(size_t)255; return q; };
    const size_t fs_bytes = (size_t)M_ROWS * 128 * 2;        // 6,144,512 B
    half_t* reg0 = (half_t*)alloc((size_t)M_ROWS * 512 * 2); // xh[24002][512] then h512
    half_t* pfs  = (half_t*)alloc((size_t)M_ROWS * 256 * 2);
    char*   rA   = alloc((size_t)M_ROWS * 256 * 2);          // bufA -> fsA|fsB -> h128
    char*   rB   = alloc((size_t)M_ROWS * 256 * 2);          // bufB -> tmp -> h256
    half_t* Wpt_t  = (half_t*)alloc((size_t)256 * 512 * 2);
    half_t* r1Wt   = (half_t*)alloc((size_t)2 * 256 * 4096 * 2);
    half_t* Wmid_t = (half_t*)alloc((size_t)128 * 256 * 2);
    half_t* rsWt   = (half_t*)alloc((size_t)6 * 128 * 2048 * 2);
    half_t* Wo1_t  = (half_t*)alloc((size_t)256 * 512 * 2);
    half_t* Wo2_t  = (half_t*)alloc((size_t)128 * 256 * 2);
    float*  pmax   = (float*)alloc((size_t)2 * 32 * 128 * 4);
    half_t* gfs    = (half_t*)alloc(512);

    half_t* bufA = (half_t*)rA;
    half_t* bufB = (half_t*)rB;
    half_t* fsA  = (half_t*)rA;            // [24002][128]
    half_t* fsB  = (half_t*)(rA + fs_bytes);
    half_t* tmp  = (half_t*)rB;
    half_t* h512 = reg0;
    half_t* h256 = (half_t*)rB;
    half_t* h128 = (half_t*)rA;

    const dim3 blk(256);

    // ---- prep: weight transpose+convert (Kpad mult of 64), x convert ----
    wcvt<<<dim3(16, 8, 1),  blk, 0, stream>>>(W_point, Wpt_t, 479, 256, 512);
    wcvt<<<dim3(128, 8, 2), blk, 0, stream>>>(res1_W, r1Wt, 4096, 256, 4096);
    wcvt<<<dim3(8, 4, 1),   blk, 0, stream>>>(W_mid, Wmid_t, 256, 128, 256);
    wcvt<<<dim3(64, 4, 6),  blk, 0, stream>>>(ress_W, rsWt, 2048, 128, 2048);
    wcvt<<<dim3(16, 8, 1),  blk, 0, stream>>>(Wo1, Wo1_t, 512, 256, 512);
    wcvt<<<dim3(8, 4, 1),   blk, 0, stream>>>(Wo2, Wo2_t, 256, 128, 256);
    cvt_x<<<M_ROWS, blk, 0, stream>>>(x, reg0);

    const int mg64 = (M_ROWS + 63) / 64;   // 376
    const int mg32 = (M_ROWS + 31) / 32;   // 751
    const int mg16 = (M_ROWS + 15) / 16;   // 1501

    // 1. pointMLP: pfs = relu(xh @ Wpt), dummy rows zeroed   [(376,4)]
    gemm_mfma<false, 64, 64, 0><<<dim3(mg64, 4), blk, 0, stream>>>(
        reg0, Wpt_t, nullptr, nullptr, nullptr, pfs,
        M_ROWS, 256, 512, 512, 1, 1);

    // 2. res1 conv a   [(376,4)] — R11 best config for the fabric-bound gather
    gemm_mfma<true, 64, 64, 8><<<dim3(mg64, 4), blk, 0, stream>>>(
        pfs, r1Wt, res1_b, nullptr, sidx, bufA,
        M_ROWS, 256, 4096, 0, 1, 1);

    // 3. res1 conv b + residual(pfs)   [(376,4)]
    gemm_mfma<true, 64, 64, 8><<<dim3(mg64, 4), blk, 0, stream>>>(
        bufA, r1Wt + (size_t)256 * 4096, res1_b + 256, pfs, sidx, bufB,
        M_ROWS, 256, 4096, 0, 1, 1);

    // 4. midDown (no bias/relu, masked)   [(751,2)]
    gemm_mfma<false, 32, 64, 0><<<dim3(mg32, 2), blk, 0, stream>>>(
        bufB, Wmid_t, nullptr, nullptr, nullptr, fsA,
        M_ROWS, 128, 256, 256, 0, 1);

    // 5. masked global max-pool
    maxpool1<<<dim3(BATCH, 32), dim3(128), 0, stream>>>(fsA, pmax);
    maxpool2<<<dim3(BATCH), dim3(128), 0, stream>>>(pmax, gfs);

    // 6. three 128-ch residual spiral blocks   [(1501,1) each — 1-pass gather]
    half_t* cur = fsA;
    half_t* nxt = fsB;
    for (int i = 0; i < 3; ++i) {
        const half_t* Wa = rsWt + (size_t)(2 * i + 0) * 128 * 2048;
        const half_t* Wb = rsWt + (size_t)(2 * i + 1) * 128 * 2048;
        const float* ba = ress_b + (2 * i + 0) * 128;
        const float* bb = ress_b + (2 * i + 1) * 128;
        gemm_mfma<true, 16, 128, 7><<<dim3(mg16, 1), blk, 0, stream>>>(
            cur, Wa, ba, nullptr, sidx, tmp,
            M_ROWS, 128, 2048, 0, 1, 1);
        gemm_mfma<true, 16, 128, 7><<<dim3(mg16, 1), blk, 0, stream>>>(
            tmp, Wb, bb, cur, sidx, nxt,
            M_ROWS, 128, 2048, 0, 1, 1);
        half_t* t2 = cur; cur = nxt; nxt = t2;
    }
    // cur == fsB

    // 7. concat -> h512 (xh region dead)
    concat_k<<<(unsigned)(((size_t)M_ROWS * 512 + 255) / 256), blk, 0, stream>>>(
        pfs, cur, gfs, h512);

    // 8. out MLP 1 (overwrites rB; tmp dead)   [(376,4)]
    gemm_mfma<false, 64, 64, 0><<<dim3(mg64, 4), blk, 0, stream>>>(
        h512, Wo1_t, bo1, nullptr, nullptr, h256,
        M_ROWS, 256, 512, 512, 1, 0);

    // 9. out MLP 2 (overwrites rA; fs dead)   [(751,2)]
    gemm_mfma<false, 32, 64, 0><<<dim3(mg32, 2), blk, 0, stream>>>(
        h256, Wo2_t, bo2, nullptr, nullptr, h128,
        M_ROWS, 128, 256, 256, 1, 0);

    // 10. final 128->3 fp32
    final_k<<<(BATCH * V + 255) / 256, blk, 0, stream>>>(h128, Wo3, bo3, out);
}

// Round 14
// 574.379 us; speedup vs baseline: 1.2077x; 1.2077x over previous
//
#include <hip/hip_runtime.h>
#include <cstdint>
#include <cfloat>
#include <cstddef>

// ---------------- problem constants ----------------
constexpr int BATCH  = 2;
constexpr int V      = 12000;
constexpr int VP     = V + 1;        // 12001
constexpr int M_ROWS = BATCH * VP;   // 24002
constexpr int L_SP   = 16;

typedef _Float16 half_t;
typedef _Float16 half8 __attribute__((ext_vector_type(8)));
typedef float floatx4 __attribute__((ext_vector_type(4)));

// async global->LDS, 16B per lane (global_load_lds_dwordx4)
__device__ __forceinline__ void async_cp16(const void* g, void* l) {
    __builtin_amdgcn_global_load_lds(
        (const __attribute__((address_space(1))) unsigned int*)g,
        (__attribute__((address_space(3))) unsigned int*)l, 16, 0, 0);
}

// ---------------------------------------------------------------------------
// f16 MFMA GEMM — R11 structure (single LDS buffer, per-iter barrier pair,
// idx VGPR prefetch, XOR swizzle; conflicts==0), BM x BN tiles, plus
// XCD-batch affinity (XSWZ): FETCH ~ passes x 8XCD x per-XCD-working-set.
// Linear block id round-robins XCDs (id%8 heuristic); xcd 0-3 -> batch 0,
// 4-7 -> batch 1, tile = (bx>>3)*4 + (xcd&3). Each XCD then gathers from ONE
// batch's table: ress 3.07MB < 4MB L2 (resident), res1 6.1 vs 12.3MB
// (miss rate ~halves). gridDim.x % 8 == 0 keeps y-tiles on the same xcd.
// R13 lesson: BM=16 halves FLOP/staged-byte — regression; ress stays BM=32.
//   GATHER: A row m=(b,v) = concat_l act[b*VP + idx[v][l], 0:C], C=2^LGC
//   else  : A is [M][KA] fp16 row-major (KA % 64 == 0); LGC=0
// Wt is [N][K] fp16 (pre-transposed). Epilogue: fp32 acc + bias(f32) +
// res(f16), optional relu, rows v==VP-1 zeroed when mask. Output fp16.
// Requires: N % BN == 0, K % 64 == 0, (GATHER) 64 | C and K/C == 16;
// XSWZ: grid.x = 2 * ceil(VP/BM), ceil(VP/BM) % 4 == 0.
// ---------------------------------------------------------------------------
template<bool GATHER, int BM, int BN, int LGC, bool XSWZ>
__global__ __launch_bounds__(256, 4)
void gemm_mfma(const half_t* __restrict__ A, const half_t* __restrict__ Wt,
               const float* __restrict__ bias, const half_t* __restrict__ res,
               const int* __restrict__ idx, half_t* __restrict__ out,
               int M, int N, int K, int KA, int relu, int mask)
{
    constexpr int AI = BM / 32;          // A stage instrs per thread
    constexpr int NB = BN / 32;          // B stage instrs per thread
    constexpr int AFR = (BM / 2) / 16;   // A frags per wave (2x2 quadrants)
    constexpr int BFR = (BN / 2) / 16;   // B frags per wave
    __shared__ half_t As[BM * 64];
    __shared__ half_t Bs[BN * 64];

    const int tid  = threadIdx.x;
    const int lane = tid & 63;
    const int w    = tid >> 6;
    const int bn   = blockIdx.y;

    // ---- M-tile mapping (XCD-batch affinity) ----
    int tile, batch;
    if (XSWZ) {
        const int xcd = blockIdx.x & 7, slot = blockIdx.x >> 3;
        batch = xcd >> 2;                    // XCDs 0-3 -> batch 0, 4-7 -> batch 1
        tile  = slot * 4 + (xcd & 3);        // within-batch tile
    } else {
        tile = blockIdx.x; batch = 0;
    }

    // swizzled 16B-chunk offset (halfs): lane stages chunk (lane&7)^((lane>>3)&7)
    const int goff = (((lane & 7) ^ ((lane >> 3) & 7)) << 3);
    const int rsub = lane >> 3;          // row within 8-row stage group

    // ---- B staging: BN rows x 128B; wave w -> instr-blocks w+4*bi ----
    const half_t* wp[NB];
    half_t* lB[NB];
#pragma unroll
    for (int bi = 0; bi < NB; ++bi) {
        const int blk = w + (bi << 2);
        wp[bi] = Wt + (size_t)(bn * BN + (blk << 3) + rsub) * K + goff;
        lB[bi] = &Bs[(size_t)((blk << 6) + lane) * 8];
    }

    // ---- A staging: BM rows; wave w -> instr-blocks w+4*ai ----
    int vv[AI], abase[AI];
    const half_t* aP[AI];
    half_t* lA[AI];
#pragma unroll
    for (int ai = 0; ai < AI; ++ai) {
        const int blk = w + (ai << 2);
        const int r = (blk << 3) + rsub;
        if (XSWZ) {
            int v = tile * BM + r; if (v >= VP) v = VP - 1;
            vv[ai] = v; abase[ai] = batch * VP;
            aP[ai] = nullptr;
        } else {
            int m = tile * BM + r; if (m >= M) m = M - 1;
            const int b = m / VP;
            vv[ai] = m - b * VP; abase[ai] = b * VP;
            aP[ai] = GATHER ? nullptr : (A + (size_t)m * KA + goff);
        }
        lA[ai] = &As[(size_t)((blk << 6) + lane) * 8];
    }

    // ---- compute mapping: 2x2 wave quadrants ----
    const int wm = (w >> 1) * (BM / 2);
    const int wn = (w & 1) * (BN / 2);
    const int fr = lane & 15;            // A row / B col within 16-tile
    const int q  = lane >> 4;            // k-quad
    const int f7 = fr & 7;

    floatx4 acc[AFR][BFR] = {};

    auto compute = [&]() {
#pragma unroll
        for (int s = 0; s < 2; ++s) {
            const int ck = ((((s << 2) | q) ^ f7) << 3);   // swizzled chunk (halfs)
            half8 af[AFR], bf[BFR];
#pragma unroll
            for (int i = 0; i < AFR; ++i)
                af[i] = *(const half8*)&As[(wm + (i << 4) + fr) * 64 + ck];
#pragma unroll
            for (int j = 0; j < BFR; ++j)
                bf[j] = *(const half8*)&Bs[(wn + (j << 4) + fr) * 64 + ck];
#pragma unroll
            for (int i = 0; i < AFR; ++i)
#pragma unroll
                for (int j = 0; j < BFR; ++j)
                    acc[i][j] = __builtin_amdgcn_mfma_f32_16x16x32_f16(af[i], bf[j], acc[i][j], 0, 0, 0);
        }
    };

    if (GATHER) {
        constexpr int NI = (1 << LGC) >> 6;   // BK=64 tiles per neighbor (4 or 2)
        constexpr int L  = 16;                // K / C
        int jc[AI], jn[AI];
#pragma unroll
        for (int ai = 0; ai < AI; ++ai) jc[ai] = idx[vv[ai] << 4];
#pragma unroll
        for (int ai = 0; ai < AI; ++ai) jn[ai] = idx[(vv[ai] << 4) + 1];
#pragma unroll 1
        for (int l = 0; l < L; ++l) {
            const half_t* g[AI];
#pragma unroll
            for (int ai = 0; ai < AI; ++ai)
                g[ai] = A + (((size_t)(abase[ai] + jc[ai])) << LGC) + goff;
            const int kb = l << LGC;
#pragma unroll
            for (int kc = 0; kc < NI; ++kc) {
#pragma unroll
                for (int ai = 0; ai < AI; ++ai)
                    async_cp16(g[ai] + (kc << 6), lA[ai]);
#pragma unroll
                for (int bi = 0; bi < NB; ++bi)
                    async_cp16(wp[bi] + kb + (kc << 6), lB[bi]);
                __syncthreads();   // drains staging (and the jn prefetch)
                compute();
                __syncthreads();   // LDS reuse guard
            }
            // rotate idx: jn was prefetched a full group ago -> zero wait here
#pragma unroll
            for (int ai = 0; ai < AI; ++ai) jc[ai] = jn[ai];
            if (l + 2 < L) {
#pragma unroll
                for (int ai = 0; ai < AI; ++ai) jn[ai] = idx[(vv[ai] << 4) + l + 2];
            }
        }
    } else {
        const int nk = K >> 6;
        for (int t = 0; t < nk; ++t) {
            const int k0 = t << 6;
#pragma unroll
            for (int ai = 0; ai < AI; ++ai)
                async_cp16(aP[ai] + k0, lA[ai]);
#pragma unroll
            for (int bi = 0; bi < NB; ++bi)
                async_cp16(wp[bi] + k0, lB[bi]);
            __syncthreads();
            compute();
            __syncthreads();
        }
    }

    // epilogue: C/D layout col=lane&15, row=(lane>>4)*4+reg
    const int er = q << 2;
#pragma unroll
    for (int i = 0; i < AFR; ++i) {
#pragma unroll
        for (int j = 0; j < BFR; ++j) {
            const int n = bn * BN + wn + (j << 4) + fr;
            const floatx4 a = acc[i][j];
#pragma unroll
            for (int r = 0; r < 4; ++r) {
                int m, vvm;
                const int mr = tile * BM + wm + (i << 4) + er + r;
                if (XSWZ) {
                    vvm = mr < VP ? mr : VP - 1;          // clamp: dup writes to dummy row
                    m = batch * VP + vvm;
                } else {
                    if (mr >= M) continue;
                    m = mr; vvm = m - (m / VP) * VP;
                }
                float val = a[r];
                if (bias) val += bias[n];
                if (res)  val += (float)res[(size_t)m * N + n];
                if (relu) val = fmaxf(val, 0.f);
                if (mask && vvm == VP - 1) val = 0.f;
                out[(size_t)m * N + n] = (half_t)val;
            }
        }
    }
}

// ---------------------------------------------------------------------------
// weight convert + transpose fp32 [z][K][N] -> fp16 [z][N][Kpad] (zero-pad K)
// grid (ceil(Kpad/32), ceil(N/32), z), block 256 (32x8)
// ---------------------------------------------------------------------------
__global__ void wcvt(const float* __restrict__ in, half_t* __restrict__ out,
                     int K, int N, int Kpad)
{
    __shared__ float t[32][33];
    const size_t ioff = (size_t)blockIdx.z * K * N;
    const size_t ooff = (size_t)blockIdx.z * N * Kpad;
    const int k0 = blockIdx.x * 32, n0 = blockIdx.y * 32;
    const int tx = threadIdx.x & 31, ty = threadIdx.x >> 5;
#pragma unroll
    for (int r = 0; r < 4; ++r) {
        const int k = k0 + ty + r * 8;
        t[ty + r * 8][tx] = (k < K && n0 + tx < N) ? in[ioff + (size_t)k * N + n0 + tx] : 0.f;
    }
    __syncthreads();
#pragma unroll
    for (int r = 0; r < 4; ++r) {
        const int n = n0 + ty + r * 8;
        const int k = k0 + tx;
        if (n < N && k < Kpad) out[ooff + (size_t)n * Kpad + k] = (half_t)t[tx][ty + r * 8];
    }
}

// x [B][V][479] fp32 -> xh [B*VP][512] fp16, pad cols 479..511 and dummy rows = 0
__global__ void cvt_x(const float* __restrict__ x, half_t* __restrict__ xh)
{
    const int m = blockIdx.x;
    const int b = m / VP, v = m - b * VP;
    for (int k = threadIdx.x; k < 512; k += 256) {
        float val = (v < V && k < 479) ? x[((size_t)b * V + v) * 479 + k] : 0.f;
        xh[(size_t)m * 512 + k] = (half_t)val;
    }
}

// masked global max-pool, 2 stages. fs fp16 [B*VP][128]
__global__ void maxpool1(const half_t* __restrict__ fs, float* __restrict__ pmax)
{
    const int b = blockIdx.x, chunk = blockIdx.y;   // grid (2,32), block 128
    const int c = threadIdx.x;
    const int v0 = chunk * (V / 32);
    float m = -FLT_MAX;
    const half_t* p = fs + ((size_t)b * VP + v0) * 128 + c;
    for (int v = 0; v < V / 32; ++v) { m = fmaxf(m, (float)*p); p += 128; }
    pmax[((size_t)b * 32 + chunk) * 128 + c] = m;
}
__global__ void maxpool2(const float* __restrict__ pmax, half_t* __restrict__ gfs)
{
    const int b = blockIdx.x, c = threadIdx.x;      // grid 2, block 128
    float m = -FLT_MAX;
    for (int i = 0; i < 32; ++i) m = fmaxf(m, pmax[((size_t)b * 32 + i) * 128 + c]);
    gfs[b * 128 + c] = (half_t)m;
}

// h512[m] = [pfs(256) | fs(128) | gfs(128)*zp]  (fp16)
__global__ void concat_k(const half_t* __restrict__ pfs, const half_t* __restrict__ fs,
                         const half_t* __restrict__ gfs, half_t* __restrict__ h)
{
    const size_t i = (size_t)blockIdx.x * 256 + threadIdx.x;
    if (i >= (size_t)M_ROWS * 512) return;
    const int    n   = (int)(i & 511);
    const size_t row = i >> 9;
    const int    b   = (int)(row / VP);
    const int    v   = (int)(row - (size_t)b * VP);
    half_t val;
    if (n < 256)      val = pfs[row * 256 + n];
    else if (n < 384) val = fs[row * 128 + (n - 256)];
    else              val = (v == VP - 1) ? (half_t)0.f : gfs[b * 128 + (n - 384)];
    h[i] = val;
}

// final 128->3 (fp32 weights for accuracy), drop dummy vertex
__global__ void final_k(const half_t* __restrict__ h, const float* __restrict__ Wo3,
                        const float* __restrict__ bo3, float* __restrict__ out)
{
    __shared__ float wsm[384];
    __shared__ float b3[3];
    for (int t = threadIdx.x; t < 384; t += 256) wsm[t] = Wo3[t];
    if (threadIdx.x < 3) b3[threadIdx.x] = bo3[threadIdx.x];
    __syncthreads();

    const int gid = blockIdx.x * 256 + threadIdx.x;
    if (gid >= BATCH * V) return;
    const int b = gid / V;
    const int v = gid - b * V;
    const half_t* hr = h + ((size_t)b * VP + v) * 128;

    float o0 = b3[0], o1 = b3[1], o2 = b3[2];
#pragma unroll 4
    for (int c = 0; c < 128; ++c) {
        const float hv = (float)hr[c];
        o0 += hv * wsm[c * 3 + 0];
        o1 += hv * wsm[c * 3 + 1];
        o2 += hv * wsm[c * 3 + 2];
    }
    out[(size_t)gid * 3 + 0] = o0;
    out[(size_t)gid * 3 + 1] = o1;
    out[(size_t)gid * 3 + 2] = o2;
}

// ---------------------------------------------------------------------------
extern "C" void kernel_launch(void* const* d_in, const int* in_sizes, int n_in,
                              void* d_out, int out_size, void* d_ws, size_t ws_size,
                              hipStream_t stream)
{
    const float* x       = (const float*)d_in[0];
    const int*   sidx    = (const int*)  d_in[1];
    const float* W_point = (const float*)d_in[2];
    const float* res1_W  = (const float*)d_in[3];
    const float* res1_b  = (const float*)d_in[4];
    const float* W_mid   = (const float*)d_in[5];
    const float* ress_W  = (const float*)d_in[6];
    const float* ress_b  = (const float*)d_in[7];
    const float* Wo1     = (const float*)d_in[8];
    const float* bo1     = (const float*)d_in[9];
    const float* Wo2     = (const float*)d_in[10];
    const float* bo2     = (const float*)d_in[11];
    const float* Wo3     = (const float*)d_in[12];
    const float* bo3     = (const float*)d_in[13];
    float* out = (float*)d_out;

    // ---- workspace carve (bytes, 256B aligned) ----
    char* p = (char*)d_ws;
    auto alloc = [&](size_t bytes) { char* q = p; p += (bytes + 255) & ~(size_t)255; return q; };
    const size_t fs_bytes = (size_t)M_ROWS * 128 * 2;        // 6,144,512 B
    half_t* reg0 = (half_t*)alloc((size_t)M_ROWS * 512 * 2); // xh[24002][512] then h512
    half_t* pfs  = (half_t*)alloc((size_t)M_ROWS * 256 * 2);
    char*   rA   = alloc((size_t)M_ROWS * 256 * 2);          // bufA -> fsA|fsB -> h128
    char*   rB   = alloc((size_t)M_ROWS * 256 * 2);          // bufB -> tmp -> h256
    half_t* Wpt_t  = (half_t*)alloc((size_t)256 * 512 * 2);
    half_t* r1Wt   = (half_t*)alloc((size_t)2 * 256 * 4096 * 2);
    half_t* Wmid_t = (half_t*)alloc((size_t)128 * 256 * 2);
    half_t* rsWt   = (half_t*)alloc((size_t)6 * 128 * 2048 * 2);
    half_t* Wo1_t  = (half_t*)alloc((size_t)256 * 512 * 2);
    half_t* Wo2_t  = (half_t*)alloc((size_t)128 * 256 * 2);
    float*  pmax   = (float*)alloc((size_t)2 * 32 * 128 * 4);
    half_t* gfs    = (half_t*)alloc(512);

    half_t* bufA = (half_t*)rA;
    half_t* bufB = (half_t*)rB;
    half_t* fsA  = (half_t*)rA;            // [24002][128]
    half_t* fsB  = (half_t*)(rA + fs_bytes);
    half_t* tmp  = (half_t*)rB;
    half_t* h512 = reg0;
    half_t* h256 = (half_t*)rB;
    half_t* h128 = (half_t*)rA;

    const dim3 blk(256);

    // ---- prep: weight transpose+convert (Kpad mult of 64), x convert ----
    wcvt<<<dim3(16, 8, 1),  blk, 0, stream>>>(W_point, Wpt_t, 479, 256, 512);
    wcvt<<<dim3(128, 8, 2), blk, 0, stream>>>(res1_W, r1Wt, 4096, 256, 4096);
    wcvt<<<dim3(8, 4, 1),   blk, 0, stream>>>(W_mid, Wmid_t, 256, 128, 256);
    wcvt<<<dim3(64, 4, 6),  blk, 0, stream>>>(ress_W, rsWt, 2048, 128, 2048);
    wcvt<<<dim3(16, 8, 1),  blk, 0, stream>>>(Wo1, Wo1_t, 512, 256, 512);
    wcvt<<<dim3(8, 4, 1),   blk, 0, stream>>>(Wo2, Wo2_t, 256, 128, 256);
    cvt_x<<<M_ROWS, blk, 0, stream>>>(x, reg0);

    const int mg64 = (M_ROWS + 63) / 64;   // 376 (non-swizzled layers)
    const int mg32 = (M_ROWS + 31) / 32;   // 751
    const int sg64 = 2 * ((VP + 63) / 64); // 376 = 2 x 188, 188 % 4 == 0
    const int sg32 = 2 * ((VP + 31) / 32); // 752 = 2 x 376, 376 % 4 == 0

    // 1. pointMLP: pfs = relu(xh @ Wpt), dummy rows zeroed   [(376,4)]
    gemm_mfma<false, 64, 64, 0, false><<<dim3(mg64, 4), blk, 0, stream>>>(
        reg0, Wpt_t, nullptr, nullptr, nullptr, pfs,
        M_ROWS, 256, 512, 512, 1, 1);

    // 2. res1 conv a   [(376,4) XCD-batch swizzled]
    gemm_mfma<true, 64, 64, 8, true><<<dim3(sg64, 4), blk, 0, stream>>>(
        pfs, r1Wt, res1_b, nullptr, sidx, bufA,
        M_ROWS, 256, 4096, 0, 1, 1);

    // 3. res1 conv b + residual(pfs)   [(376,4) swizzled]
    gemm_mfma<true, 64, 64, 8, true><<<dim3(sg64, 4), blk, 0, stream>>>(
        bufA, r1Wt + (size_t)256 * 4096, res1_b + 256, pfs, sidx, bufB,
        M_ROWS, 256, 4096, 0, 1, 1);

    // 4. midDown (no bias/relu, masked)   [(751,2)]
    gemm_mfma<false, 32, 64, 0, false><<<dim3(mg32, 2), blk, 0, stream>>>(
        bufB, Wmid_t, nullptr, nullptr, nullptr, fsA,
        M_ROWS, 128, 256, 256, 0, 1);

    // 5. masked global max-pool
    maxpool1<<<dim3(BATCH, 32), dim3(128), 0, stream>>>(fsA, pmax);
    maxpool2<<<dim3(BATCH), dim3(128), 0, stream>>>(pmax, gfs);

    // 6. three 128-ch residual spiral blocks   [(752,2) swizzled each]
    half_t* cur = fsA;
    half_t* nxt = fsB;
    for (int i = 0; i < 3; ++i) {
        const half_t* Wa = rsWt + (size_t)(2 * i + 0) * 128 * 2048;
        const half_t* Wb = rsWt + (size_t)(2 * i + 1) * 128 * 2048;
        const float* ba = ress_b + (2 * i + 0) * 128;
        const float* bb = ress_b + (2 * i + 1) * 128;
        gemm_mfma<true, 32, 64, 7, true><<<dim3(sg32, 2), blk, 0, stream>>>(
            cur, Wa, ba, nullptr, sidx, tmp,
            M_ROWS, 128, 2048, 0, 1, 1);
        gemm_mfma<true, 32, 64, 7, true><<<dim3(sg32, 2), blk, 0, stream>>>(
            tmp, Wb, bb, cur, sidx, nxt,
            M_ROWS, 128, 2048, 0, 1, 1);
        half_t* t2 = cur; cur = nxt; nxt = t2;
    }
    // cur == fsB

    // 7. concat -> h512 (xh region dead)
    concat_k<<<(unsigned)(((size_t)M_ROWS * 512 + 255) / 256), blk, 0, stream>>>(
        pfs, cur, gfs, h512);

    // 8. out MLP 1 (overwrites rB; tmp dead)   [(376,4)]
    gemm_mfma<false, 64, 64, 0, false><<<dim3(mg64, 4), blk, 0, stream>>>(
        h512, Wo1_t, bo1, nullptr, nullptr, h256,
        M_ROWS, 256, 512, 512, 1, 0);

    // 9. out MLP 2 (overwrites rA; fs dead)   [(751,2)]
    gemm_mfma<false, 32, 64, 0, false><<<dim3(mg32, 2), blk, 0, stream>>>(
        h256, Wo2_t, bo2, nullptr, nullptr, h128,
        M_ROWS, 128, 256, 256, 1, 0);

    // 10. final 128->3 fp32
    final_k<<<(BATCH * V + 255) / 256, blk, 0, stream>>>(h128, Wo3, bo3, out);
}